// Round 1
// baseline (83.589 us; speedup 1.0000x reference)
//
#include <hip/hip_runtime.h>
#include <math.h>

#define BB 4
#define NQ 256
#define NK 1024
#define DD 256
#define HH 256

// ---------------- Projection GEMM (fp32) + tanh epilogue ----------------
// C[m,h] = clamp(tanh( sum_d A[m,d] * W[d,h] ))
// A: [M,256] row-major, W: [256,256] row-major, C: [M,256]
#define TM 64
#define TN 64
#define TKK 16

__global__ __launch_bounds__(256) void proj_tanh_kernel(
    const float* __restrict__ Q, const float* __restrict__ K,
    const float* __restrict__ Wq, const float* __restrict__ Wk,
    float* __restrict__ tq, float* __restrict__ tk)
{
    const int QTILES = (BB * NQ) / TM;   // 16
    int bx = blockIdx.x;
    const float* A; const float* W; float* C; int bm;
    if (bx < QTILES) { A = Q; W = Wq; C = tq; bm = bx * TM; }
    else             { A = K; W = Wk; C = tk; bm = (bx - QTILES) * TM; }
    int bn = blockIdx.y * TN;

    __shared__ float As[TKK][TM + 1];   // +1 pad: avoid 16-way store conflicts
    __shared__ float Ws[TKK][TN];

    int tid = threadIdx.x;
    int tx = tid & 15;        // output col group
    int ty = tid >> 4;        // output row group
    int la_c = tid & 15;      // A loader: k within tile
    int la_r = tid >> 4;      // A loader: row base
    int lw_c = tid & 63;      // W loader: n
    int lw_r = tid >> 6;      // W loader: k base

    float acc[4][4] = {};

    for (int k0 = 0; k0 < DD; k0 += TKK) {
        __syncthreads();
#pragma unroll
        for (int i = 0; i < 4; ++i) {
            int r = la_r + 16 * i;
            As[la_c][r] = A[(size_t)(bm + r) * DD + k0 + la_c];
        }
#pragma unroll
        for (int i = 0; i < 4; ++i) {
            int kk = lw_r + 4 * i;
            Ws[kk][lw_c] = W[(size_t)(k0 + kk) * HH + bn + lw_c];
        }
        __syncthreads();
#pragma unroll
        for (int kk = 0; kk < TKK; ++kk) {
            float a[4], w[4];
#pragma unroll
            for (int i = 0; i < 4; ++i) a[i] = As[kk][ty + 16 * i];
#pragma unroll
            for (int j = 0; j < 4; ++j) w[j] = Ws[kk][tx + 16 * j];
#pragma unroll
            for (int i = 0; i < 4; ++i)
#pragma unroll
                for (int j = 0; j < 4; ++j)
                    acc[i][j] = fmaf(a[i], w[j], acc[i][j]);
        }
    }

#pragma unroll
    for (int i = 0; i < 4; ++i) {
        int m = bm + ty + 16 * i;
#pragma unroll
        for (int j = 0; j < 4; ++j) {
            int n = bn + tx + 16 * j;
            float t = tanhf(acc[i][j]);
            // NaN guard for the tanh-addition formula: keep |t| < 1 strictly
            t = fminf(fmaxf(t, -0.999999f), 0.999999f);
            C[(size_t)m * HH + n] = t;
        }
    }
}

// ---------------- Fused scores + masked softmax + PV ----------------
// Per block: one batch b, QT consecutive q rows. Skips all k >= valid_len[b]
// (their softmax weight is exactly 0 in f32: exp(-1e6 - m) underflows).
#define QT 2

__device__ __forceinline__ float waveReduceMax(float v) {
#pragma unroll
    for (int o = 32; o; o >>= 1) v = fmaxf(v, __shfl_xor(v, o, 64));
    return v;
}
__device__ __forceinline__ float waveReduceSum(float v) {
#pragma unroll
    for (int o = 32; o; o >>= 1) v += __shfl_xor(v, o, 64);
    return v;
}
__device__ __forceinline__ float blockReduceMax(float v, float* s, int tid) {
    v = waveReduceMax(v);
    __syncthreads();                       // guard scratch reuse
    if ((tid & 63) == 0) s[tid >> 6] = v;
    __syncthreads();
    return fmaxf(fmaxf(s[0], s[1]), fmaxf(s[2], s[3]));
}
__device__ __forceinline__ float blockReduceSum(float v, float* s, int tid) {
    v = waveReduceSum(v);
    __syncthreads();
    if ((tid & 63) == 0) s[tid >> 6] = v;
    __syncthreads();
    return (s[0] + s[1]) + (s[2] + s[3]);
}

__global__ __launch_bounds__(256) void attn_kernel(
    const float* __restrict__ tq,    // [B,NQ,H] tanh(q proj)
    const float* __restrict__ tk,    // [B,NK,H] tanh(k proj)
    const float* __restrict__ V,     // [B,NK,D]
    const int*   __restrict__ vlen,  // [B]
    const float* __restrict__ wv,    // [H]
    float* __restrict__ out)         // [B,NQ,D]
{
    __shared__ __align__(16) float sS[QT][NK];
    __shared__ __align__(16) float sTq[QT][HH];
    __shared__ __align__(16) float sWv[HH];
    __shared__ float sRed[4];

    int tid = threadIdx.x;
    int bid = blockIdx.x;
    int b  = bid & (BB - 1);            // interleave batches for load balance
    int q0 = (bid >> 2) * QT;
    int L  = vlen[b];

    sWv[tid] = wv[tid];
#pragma unroll
    for (int qq = 0; qq < QT; ++qq)
        sTq[qq][tid] = tq[((size_t)b * NQ + q0 + qq) * HH + tid];
    __syncthreads();

    const float4* sWv4 = (const float4*)sWv;
    const float4* sT0  = (const float4*)sTq[0];
    const float4* sT1  = (const float4*)sTq[1];

    // ---- phase 1: scores for k < L, thread-strided over k ----
    float m0 = -INFINITY, m1 = -INFINITY;
    for (int k = tid; k < L; k += 256) {
        const float4* kr = (const float4*)(tk + ((size_t)b * NK + k) * HH);
        float acc0 = 0.f, acc1 = 0.f;
#pragma unroll 4
        for (int h4 = 0; h4 < HH / 4; ++h4) {
            float4 kv = kr[h4];
            float4 w  = sWv4[h4];
            float4 a0 = sT0[h4];
            float4 a1 = sT1[h4];
            // tanh(a+b) = (ta+tb)/(1+ta*tb); weight by w_v, accumulate
            acc0 = fmaf(w.x * (a0.x + kv.x), __builtin_amdgcn_rcpf(fmaf(a0.x, kv.x, 1.f)), acc0);
            acc0 = fmaf(w.y * (a0.y + kv.y), __builtin_amdgcn_rcpf(fmaf(a0.y, kv.y, 1.f)), acc0);
            acc0 = fmaf(w.z * (a0.z + kv.z), __builtin_amdgcn_rcpf(fmaf(a0.z, kv.z, 1.f)), acc0);
            acc0 = fmaf(w.w * (a0.w + kv.w), __builtin_amdgcn_rcpf(fmaf(a0.w, kv.w, 1.f)), acc0);
            acc1 = fmaf(w.x * (a1.x + kv.x), __builtin_amdgcn_rcpf(fmaf(a1.x, kv.x, 1.f)), acc1);
            acc1 = fmaf(w.y * (a1.y + kv.y), __builtin_amdgcn_rcpf(fmaf(a1.y, kv.y, 1.f)), acc1);
            acc1 = fmaf(w.z * (a1.z + kv.z), __builtin_amdgcn_rcpf(fmaf(a1.z, kv.z, 1.f)), acc1);
            acc1 = fmaf(w.w * (a1.w + kv.w), __builtin_amdgcn_rcpf(fmaf(a1.w, kv.w, 1.f)), acc1);
        }
        sS[0][k] = acc0; sS[1][k] = acc1;
        m0 = fmaxf(m0, acc0); m1 = fmaxf(m1, acc1);
    }

    // ---- phase 2: softmax (max, exp, sum) ----
    m0 = blockReduceMax(m0, sRed, tid);
    m1 = blockReduceMax(m1, sRed, tid);
    float l0 = 0.f, l1 = 0.f;
    for (int k = tid; k < L; k += 256) {
        float p0 = __expf(sS[0][k] - m0); sS[0][k] = p0; l0 += p0;
        float p1 = __expf(sS[1][k] - m1); sS[1][k] = p1; l1 += p1;
    }
    l0 = blockReduceSum(l0, sRed, tid);   // barriers also publish sS writes
    l1 = blockReduceSum(l1, sRed, tid);

    // ---- phase 3: PV. thread <-> output dim d ----
    float acc0 = 0.f, acc1 = 0.f;
    const float* Vb = V + (size_t)b * NK * DD + tid;
#pragma unroll 4
    for (int k = 0; k < L; ++k) {
        float vv = Vb[(size_t)k * DD];
        acc0 = fmaf(sS[0][k], vv, acc0);
        acc1 = fmaf(sS[1][k], vv, acc1);
    }
    out[((size_t)b * NQ + q0) * DD + tid]     = acc0 / l0;
    out[((size_t)b * NQ + q0 + 1) * DD + tid] = acc1 / l1;
}

extern "C" void kernel_launch(void* const* d_in, const int* in_sizes, int n_in,
                              void* d_out, int out_size, void* d_ws, size_t ws_size,
                              hipStream_t stream) {
    const float* queries = (const float*)d_in[0];  // [B,NQ,D]
    const float* keys    = (const float*)d_in[1];  // [B,NK,D]
    const float* values  = (const float*)d_in[2];  // [B,NK,D]
    const int*   vlens   = (const int*)d_in[3];    // [B]
    const float* Wq      = (const float*)d_in[4];  // [D,H]
    const float* Wk      = (const float*)d_in[5];  // [D,H]
    const float* wv      = (const float*)d_in[6];  // [H]
    float* out = (float*)d_out;

    float* tq = (float*)d_ws;                          // B*NQ*H floats (1 MB)
    float* tk = tq + (size_t)BB * NQ * HH;             // B*NK*H floats (4 MB)

    // projections + tanh (q tiles and k tiles in one grid)
    dim3 pgrid((BB * NQ) / TM + (BB * NK) / TM, HH / TN);
    proj_tanh_kernel<<<pgrid, 256, 0, stream>>>(queries, keys, Wq, Wk, tq, tk);

    // fused scores + masked softmax + PV
    attn_kernel<<<dim3((BB * NQ) / QT), 256, 0, stream>>>(tq, tk, values, vlens, wv, out);
}

// Round 2
// 82.429 us; speedup vs baseline: 1.0141x; 1.0141x over previous
//
#include <hip/hip_runtime.h>
#include <math.h>

#define BB 4
#define NQ 256
#define NK 1024
#define DD 256
#define HH 256

// ---------------- K1: Projection GEMM (fp32) + tanh epilogue ----------------
#define TM 64
#define TN 64
#define TKK 16

__global__ __launch_bounds__(256) void proj_tanh_kernel(
    const float* __restrict__ Q, const float* __restrict__ K,
    const float* __restrict__ Wq, const float* __restrict__ Wk,
    float* __restrict__ tq, float* __restrict__ tk)
{
    const int QTILES = (BB * NQ) / TM;   // 16
    int bx = blockIdx.x;
    const float* A; const float* W; float* C; int bm;
    if (bx < QTILES) { A = Q; W = Wq; C = tq; bm = bx * TM; }
    else             { A = K; W = Wk; C = tk; bm = (bx - QTILES) * TM; }
    int bn = blockIdx.y * TN;

    __shared__ float As[TKK][TM + 1];
    __shared__ float Ws[TKK][TN];

    int tid = threadIdx.x;
    int tx = tid & 15;
    int ty = tid >> 4;
    int la_c = tid & 15;
    int la_r = tid >> 4;
    int lw_c = tid & 63;
    int lw_r = tid >> 6;

    float acc[4][4] = {};

    for (int k0 = 0; k0 < DD; k0 += TKK) {
        __syncthreads();
#pragma unroll
        for (int i = 0; i < 4; ++i) {
            int r = la_r + 16 * i;
            As[la_c][r] = A[(size_t)(bm + r) * DD + k0 + la_c];
        }
#pragma unroll
        for (int i = 0; i < 4; ++i) {
            int kk = lw_r + 4 * i;
            Ws[kk][lw_c] = W[(size_t)(k0 + kk) * HH + bn + lw_c];
        }
        __syncthreads();
#pragma unroll
        for (int kk = 0; kk < TKK; ++kk) {
            float a[4], w[4];
#pragma unroll
            for (int i = 0; i < 4; ++i) a[i] = As[kk][ty + 16 * i];
#pragma unroll
            for (int j = 0; j < 4; ++j) w[j] = Ws[kk][tx + 16 * j];
#pragma unroll
            for (int i = 0; i < 4; ++i)
#pragma unroll
                for (int j = 0; j < 4; ++j)
                    acc[i][j] = fmaf(a[i], w[j], acc[i][j]);
        }
    }

#pragma unroll
    for (int i = 0; i < 4; ++i) {
        int m = bm + ty + 16 * i;
#pragma unroll
        for (int j = 0; j < 4; ++j) {
            int n = bn + tx + 16 * j;
            float t = tanhf(acc[i][j]);
            t = fminf(fmaxf(t, -0.999999f), 0.999999f);   // denom-zero guard
            C[(size_t)m * HH + n] = t;
        }
    }
}

// ---------------- K2: scores tile kernel ----------------
// Block = (b, 32 q-rows, 32 k-rows). Both tiles in LDS; 2x2 micro per thread.
// score[q,k] = sum_h w[h] * (tq+tk)/(1+tq*tk)
#define QC 32
#define KC 32
#define RPAD 4   // row pad (floats), keeps 16B alignment, shifts banks by 4/row

__device__ __forceinline__ float term(float a, float b, float w, float acc) {
    return fmaf(w * (a + b), __builtin_amdgcn_rcpf(fmaf(a, b, 1.f)), acc);
}

__global__ __launch_bounds__(256) void scores_kernel(
    const float* __restrict__ tq, const float* __restrict__ tk,
    const float* __restrict__ wv, const int* __restrict__ vlen,
    float* __restrict__ S)
{
    __shared__ __align__(16) float sQ[QC][HH + RPAD];
    __shared__ __align__(16) float sK[KC][HH + RPAD];
    __shared__ __align__(16) float sW[HH];

    int bid = blockIdx.x;
    int b = bid & 3;                 // batch-interleaved for load balance
    int rest = bid >> 2;             // 0..255
    int qc = rest & 7;               // 8 q-chunks
    int kc = rest >> 3;              // 32 k-chunks
    int L = vlen[b];
    int k0 = kc * KC;
    if (k0 >= L) return;             // uniform exit: masked-out chunk
    int q0 = qc * QC;

    int tid = threadIdx.x;
    {
        int c4 = tid & 63;           // float4 column
        int r0 = tid >> 6;           // 0..3
        const float4* gq = (const float4*)(tq + ((size_t)b * NQ + q0) * HH);
        const float4* gk = (const float4*)(tk + ((size_t)b * NK + k0) * HH);
#pragma unroll
        for (int r = 0; r < QC; r += 4)
            *(float4*)&sQ[r + r0][c4 * 4] = gq[(size_t)(r + r0) * 64 + c4];
#pragma unroll
        for (int r = 0; r < KC; r += 4)
            *(float4*)&sK[r + r0][c4 * 4] = gk[(size_t)(r + r0) * 64 + c4];
        sW[tid] = wv[tid];
    }
    __syncthreads();

    int qi = tid >> 4;   // 0..15
    int ki = tid & 15;   // 0..15
    float a00 = 0.f, a01 = 0.f, a10 = 0.f, a11 = 0.f;
    const float4* q0p = (const float4*)&sQ[qi][0];
    const float4* q1p = (const float4*)&sQ[qi + 16][0];
    const float4* k0p = (const float4*)&sK[ki][0];
    const float4* k1p = (const float4*)&sK[ki + 16][0];
    const float4* wp  = (const float4*)sW;

#pragma unroll 2
    for (int h4 = 0; h4 < HH / 4; ++h4) {
        float4 w  = wp[h4];
        float4 A0 = q0p[h4], A1 = q1p[h4];
        float4 B0 = k0p[h4], B1 = k1p[h4];
        a00 = term(A0.x, B0.x, w.x, a00); a00 = term(A0.y, B0.y, w.y, a00);
        a00 = term(A0.z, B0.z, w.z, a00); a00 = term(A0.w, B0.w, w.w, a00);
        a01 = term(A0.x, B1.x, w.x, a01); a01 = term(A0.y, B1.y, w.y, a01);
        a01 = term(A0.z, B1.z, w.z, a01); a01 = term(A0.w, B1.w, w.w, a01);
        a10 = term(A1.x, B0.x, w.x, a10); a10 = term(A1.y, B0.y, w.y, a10);
        a10 = term(A1.z, B0.z, w.z, a10); a10 = term(A1.w, B0.w, w.w, a10);
        a11 = term(A1.x, B1.x, w.x, a11); a11 = term(A1.y, B1.y, w.y, a11);
        a11 = term(A1.z, B1.z, w.z, a11); a11 = term(A1.w, B1.w, w.w, a11);
    }

    int qA = q0 + qi, qB = q0 + qi + 16;
    int kA = k0 + ki, kB = k0 + ki + 16;
    float* Sq0 = S + ((size_t)b * NQ + qA) * NK;
    float* Sq1 = S + ((size_t)b * NQ + qB) * NK;
    Sq0[kA] = a00; Sq0[kB] = a01;
    Sq1[kA] = a10; Sq1[kB] = a11;
}

// ---------------- K3: masked softmax, one wave per q-row ----------------
__device__ __forceinline__ float waveReduceMax(float v) {
#pragma unroll
    for (int o = 32; o; o >>= 1) v = fmaxf(v, __shfl_xor(v, o, 64));
    return v;
}
__device__ __forceinline__ float waveReduceSum(float v) {
#pragma unroll
    for (int o = 32; o; o >>= 1) v += __shfl_xor(v, o, 64);
    return v;
}

__global__ __launch_bounds__(256) void softmax_kernel(
    float* __restrict__ S, const int* __restrict__ vlen)
{
    int tid = threadIdx.x;
    int lane = tid & 63, wid = tid >> 6;
    int bid = blockIdx.x;            // 256 blocks
    int b = bid & 3;
    int qg = bid >> 2;               // 0..63
    int q = qg * 4 + wid;
    int L = vlen[b];
    float* row = S + ((size_t)b * NQ + q) * NK;

    float e[16];
    float m = -INFINITY;
#pragma unroll
    for (int i = 0; i < 16; ++i) {
        int c = lane + 64 * i;
        float v = (c < L) ? row[c] : -INFINITY;
        e[i] = v; m = fmaxf(m, v);
    }
    m = waveReduceMax(m);
    float s = 0.f;
#pragma unroll
    for (int i = 0; i < 16; ++i) {
        float p = __expf(e[i] - m);   // exp(-inf)=0 for masked cols
        e[i] = p; s += p;
    }
    s = waveReduceSum(s);
    float r = 1.0f / s;
#pragma unroll
    for (int i = 0; i < 16; ++i) {
        int c = lane + 64 * i;
        if (c < L) row[c] = e[i] * r;
    }
}

// ---------------- K4: PV tiled GEMM (fp32), skip k >= L ----------------
#define VPAD 4
__global__ __launch_bounds__(256) void pv_kernel(
    const float* __restrict__ S, const float* __restrict__ V,
    const int* __restrict__ vlen, float* __restrict__ out)
{
    __shared__ __align__(16) float sP[32][32 + VPAD];
    __shared__ __align__(16) float sVt[32][32 + VPAD];   // transposed [d][k]

    int tid = threadIdx.x;
    int bid = blockIdx.x;
    int b = bid & 3;
    int rest = bid >> 2;     // 0..63
    int qt = rest >> 3;      // 0..7
    int dt = rest & 7;       // 0..7
    int q0 = qt * 32, d0 = dt * 32;
    int L = vlen[b];

    int qi = tid >> 4, di = tid & 15;
    float a00 = 0.f, a01 = 0.f, a10 = 0.f, a11 = 0.f;

    int r  = tid >> 3;       // 0..31 staging row
    int c4 = tid & 7;        // 0..7 staging f4 col

    for (int k0 = 0; k0 < L; k0 += 32) {
        __syncthreads();
        {
            const float* prow = S + ((size_t)b * NQ + q0 + r) * NK + k0;
            int kbase = k0 + c4 * 4;
            float4 p;
            if (kbase + 3 < L) {
                p = *(const float4*)(prow + c4 * 4);
            } else {
                p.x = (kbase + 0 < L) ? prow[c4 * 4 + 0] : 0.f;
                p.y = (kbase + 1 < L) ? prow[c4 * 4 + 1] : 0.f;
                p.z = (kbase + 2 < L) ? prow[c4 * 4 + 2] : 0.f;
                p.w = (kbase + 3 < L) ? prow[c4 * 4 + 3] : 0.f;
            }
            *(float4*)&sP[r][c4 * 4] = p;

            const float* vrow = V + ((size_t)b * NK + k0 + r) * DD + d0;
            float4 vv = *(const float4*)(vrow + c4 * 4);
            sVt[c4 * 4 + 0][r] = vv.x;
            sVt[c4 * 4 + 1][r] = vv.y;
            sVt[c4 * 4 + 2][r] = vv.z;
            sVt[c4 * 4 + 3][r] = vv.w;
        }
        __syncthreads();

        const float4* pa0 = (const float4*)&sP[qi][0];
        const float4* pa1 = (const float4*)&sP[qi + 16][0];
        const float4* pb0 = (const float4*)&sVt[di][0];
        const float4* pb1 = (const float4*)&sVt[di + 16][0];
#pragma unroll
        for (int kk4 = 0; kk4 < 8; ++kk4) {
            float4 A0 = pa0[kk4], A1 = pa1[kk4];
            float4 B0 = pb0[kk4], B1 = pb1[kk4];
            a00 = fmaf(A0.x, B0.x, a00); a00 = fmaf(A0.y, B0.y, a00);
            a00 = fmaf(A0.z, B0.z, a00); a00 = fmaf(A0.w, B0.w, a00);
            a01 = fmaf(A0.x, B1.x, a01); a01 = fmaf(A0.y, B1.y, a01);
            a01 = fmaf(A0.z, B1.z, a01); a01 = fmaf(A0.w, B1.w, a01);
            a10 = fmaf(A1.x, B0.x, a10); a10 = fmaf(A1.y, B0.y, a10);
            a10 = fmaf(A1.z, B0.z, a10); a10 = fmaf(A1.w, B0.w, a10);
            a11 = fmaf(A1.x, B1.x, a11); a11 = fmaf(A1.y, B1.y, a11);
            a11 = fmaf(A1.z, B1.z, a11); a11 = fmaf(A1.w, B1.w, a11);
        }
    }

    int qA = q0 + qi, qB = q0 + qi + 16;
    int dA = d0 + di, dB = d0 + di + 16;
    float* o0 = out + ((size_t)b * NQ + qA) * DD;
    float* o1 = out + ((size_t)b * NQ + qB) * DD;
    o0[dA] = a00; o0[dB] = a01;
    o1[dA] = a10; o1[dB] = a11;
}

extern "C" void kernel_launch(void* const* d_in, const int* in_sizes, int n_in,
                              void* d_out, int out_size, void* d_ws, size_t ws_size,
                              hipStream_t stream) {
    const float* queries = (const float*)d_in[0];  // [B,NQ,D]
    const float* keys    = (const float*)d_in[1];  // [B,NK,D]
    const float* values  = (const float*)d_in[2];  // [B,NK,D]
    const int*   vlens   = (const int*)d_in[3];    // [B]
    const float* Wq      = (const float*)d_in[4];  // [D,H]
    const float* Wk      = (const float*)d_in[5];  // [D,H]
    const float* wv      = (const float*)d_in[6];  // [H]
    float* out = (float*)d_out;

    float* tq = (float*)d_ws;                             // 1 MB
    float* tk = tq + (size_t)BB * NQ * HH;                // 4 MB
    float* S  = tk + (size_t)BB * NK * HH;                // 4 MB

    dim3 pgrid((BB * NQ) / TM + (BB * NK) / TM, HH / TN);
    proj_tanh_kernel<<<pgrid, 256, 0, stream>>>(queries, keys, Wq, Wk, tq, tk);

    scores_kernel<<<dim3(BB * (NQ / QC) * (NK / KC)), 256, 0, stream>>>(
        tq, tk, wv, vlens, S);

    softmax_kernel<<<dim3(BB * NQ / 4), 256, 0, stream>>>(S, vlens);

    pv_kernel<<<dim3(BB * (NQ / 32) * (DD / 32)), 256, 0, stream>>>(
        S, values, vlens, out);
}

// Round 3
// 60.640 us; speedup vs baseline: 1.3785x; 1.3593x over previous
//
#include <hip/hip_runtime.h>
#include <math.h>

#define BB 4
#define NQ 256
#define NK 1024
#define DD 256
#define HH 256

// ---------------- K1: Projection GEMM (fp32) + tanh epilogue ----------------
// C[m,h] = clamp(tanh(sum_d A[m,d]*W[d,h])). Double-buffered LDS, 4x4 micro
// with b128 LDS reads (2B/FMA).
#define TM 64
#define TN 64
#define TKK 16
#define NT (DD / TKK)   // 16 k-steps

__global__ __launch_bounds__(256) void proj_tanh_kernel(
    const float* __restrict__ Q, const float* __restrict__ K,
    const float* __restrict__ Wq, const float* __restrict__ Wk,
    float* __restrict__ tq, float* __restrict__ tk)
{
    const int QTILES = (BB * NQ) / TM;   // 16
    int bx = blockIdx.x;
    const float* A; const float* W; float* C; int bm;
    if (bx < QTILES) { A = Q; W = Wq; C = tq; bm = bx * TM; }
    else             { A = K; W = Wk; C = tk; bm = (bx - QTILES) * TM; }
    int bn = blockIdx.y * TN;

    __shared__ float As[2][TKK][TM + 4];   // [k][m], +4 keeps 16B align, spreads banks
    __shared__ float Ws[2][TKK][TN + 4];   // [k][n]

    int tid = threadIdx.x;
    int ar = tid >> 2, ac4 = tid & 3;      // A stager: row, k-f4
    int wkk = tid >> 4, wc4 = tid & 15;    // W stager: k-row, n-f4
    int ty = tid >> 4, tx = tid & 15;      // compute: 4 contig rows/cols each

    float4 aR = *(const float4*)&A[(size_t)(bm + ar) * DD + ac4 * 4];
    float4 wR = *(const float4*)&W[(size_t)wkk * HH + bn + wc4 * 4];

    float acc[4][4] = {};

    for (int t = 0; t < NT; ++t) {
        int cur = t & 1;
        As[cur][ac4 * 4 + 0][ar] = aR.x;
        As[cur][ac4 * 4 + 1][ar] = aR.y;
        As[cur][ac4 * 4 + 2][ar] = aR.z;
        As[cur][ac4 * 4 + 3][ar] = aR.w;
        *(float4*)&Ws[cur][wkk][wc4 * 4] = wR;
        if (t + 1 < NT) {
            int k0 = (t + 1) * TKK;
            aR = *(const float4*)&A[(size_t)(bm + ar) * DD + k0 + ac4 * 4];
            wR = *(const float4*)&W[(size_t)(k0 + wkk) * HH + bn + wc4 * 4];
        }
        __syncthreads();
#pragma unroll
        for (int kk = 0; kk < TKK; ++kk) {
            float4 a4 = *(const float4*)&As[cur][kk][ty * 4];
            float4 w4 = *(const float4*)&Ws[cur][kk][tx * 4];
            acc[0][0] = fmaf(a4.x, w4.x, acc[0][0]);
            acc[0][1] = fmaf(a4.x, w4.y, acc[0][1]);
            acc[0][2] = fmaf(a4.x, w4.z, acc[0][2]);
            acc[0][3] = fmaf(a4.x, w4.w, acc[0][3]);
            acc[1][0] = fmaf(a4.y, w4.x, acc[1][0]);
            acc[1][1] = fmaf(a4.y, w4.y, acc[1][1]);
            acc[1][2] = fmaf(a4.y, w4.z, acc[1][2]);
            acc[1][3] = fmaf(a4.y, w4.w, acc[1][3]);
            acc[2][0] = fmaf(a4.z, w4.x, acc[2][0]);
            acc[2][1] = fmaf(a4.z, w4.y, acc[2][1]);
            acc[2][2] = fmaf(a4.z, w4.z, acc[2][2]);
            acc[2][3] = fmaf(a4.z, w4.w, acc[2][3]);
            acc[3][0] = fmaf(a4.w, w4.x, acc[3][0]);
            acc[3][1] = fmaf(a4.w, w4.y, acc[3][1]);
            acc[3][2] = fmaf(a4.w, w4.z, acc[3][2]);
            acc[3][3] = fmaf(a4.w, w4.w, acc[3][3]);
        }
    }

#pragma unroll
    for (int i = 0; i < 4; ++i) {
        int m = bm + ty * 4 + i;
        float4 o;
        float t0 = tanhf(acc[i][0]), t1 = tanhf(acc[i][1]);
        float t2 = tanhf(acc[i][2]), t3 = tanhf(acc[i][3]);
        // denom-zero guard for the tanh-addition identity downstream
        o.x = fminf(fmaxf(t0, -0.999999f), 0.999999f);
        o.y = fminf(fmaxf(t1, -0.999999f), 0.999999f);
        o.z = fminf(fmaxf(t2, -0.999999f), 0.999999f);
        o.w = fminf(fmaxf(t3, -0.999999f), 0.999999f);
        *(float4*)&C[(size_t)m * HH + bn + tx * 4] = o;
    }
}

// ---------------- K2: scores -> P = exp(score), + per-chunk row sums --------
// score[q,k] = sum_h w[h]*(tq+tk)/(1+tq*tk); |score| <= ||w||_1 ~ 13, so
// exp() without max-subtraction cannot overflow f32 (identical math to
// softmax with max-shift). Masked k -> P = 0. Deterministic Psum via shfl.
__device__ __forceinline__ float pairterm(float a1, float b1, float w1,
                                          float a2, float b2, float w2, float acc) {
    // w1*t1 + w2*t2 = (n1*d2 + n2*d1) / (d1*d2), t=(a+b)/(1+ab): halves rcp count
    float d1 = fmaf(a1, b1, 1.f);
    float d2 = fmaf(a2, b2, 1.f);
    float n1 = w1 * (a1 + b1);
    float n2 = w2 * (a2 + b2);
    float num = fmaf(n2, d1, n1 * d2);
    return fmaf(num, __builtin_amdgcn_rcpf(d1 * d2), acc);
}
__device__ __forceinline__ float pair2(float4 A, float4 B, float4 w, float acc) {
    acc = pairterm(A.x, B.x, w.x, A.y, B.y, w.y, acc);
    acc = pairterm(A.z, B.z, w.z, A.w, B.w, w.w, acc);
    return acc;
}

__global__ __launch_bounds__(256) void scores_kernel(
    const float* __restrict__ tq, const float* __restrict__ tk,
    const float* __restrict__ wv, const int* __restrict__ vlen,
    float* __restrict__ St, float* __restrict__ Psum)
{
    __shared__ __align__(16) float sQ[32][HH + 4];
    __shared__ __align__(16) float sK[32][HH + 4];
    __shared__ __align__(16) float sW[HH];

    int bid = blockIdx.x;
    int b = bid & 3;
    int rest = bid >> 2;
    int qc = rest & 7;
    int kc = rest >> 3;
    int L = vlen[b];
    int k0 = kc * 32;
    if (k0 >= L) return;        // whole chunk masked: uniform exit
    int q0 = qc * 32;

    int tid = threadIdx.x;
    {
        int c4 = tid & 63, r0 = tid >> 6;
        const float4* gq = (const float4*)(tq + ((size_t)b * NQ + q0) * HH);
        const float4* gk = (const float4*)(tk + ((size_t)b * NK + k0) * HH);
#pragma unroll
        for (int r = 0; r < 32; r += 4) {
            *(float4*)&sQ[r + r0][c4 * 4] = gq[(size_t)(r + r0) * (HH / 4) + c4];
            *(float4*)&sK[r + r0][c4 * 4] = gk[(size_t)(r + r0) * (HH / 4) + c4];
        }
        sW[tid] = wv[tid];
    }
    __syncthreads();

    int ki = tid & 15, qi = tid >> 4;
    float a00 = 0.f, a01 = 0.f, a10 = 0.f, a11 = 0.f;
    const float4* qp0 = (const float4*)&sQ[qi][0];
    const float4* qp1 = (const float4*)&sQ[qi + 16][0];
    const float4* kp0 = (const float4*)&sK[ki][0];
    const float4* kp1 = (const float4*)&sK[ki + 16][0];
    const float4* wp  = (const float4*)sW;

#pragma unroll 4
    for (int h = 0; h < HH / 4; ++h) {
        float4 w4 = wp[h];
        float4 A0 = qp0[h], A1 = qp1[h];
        float4 B0 = kp0[h], B1 = kp1[h];
        a00 = pair2(A0, B0, w4, a00);
        a01 = pair2(A0, B1, w4, a01);
        a10 = pair2(A1, B0, w4, a10);
        a11 = pair2(A1, B1, w4, a11);
    }

    int kA = k0 + ki, kB = kA + 16;
    float p00 = (kA < L) ? __expf(a00) : 0.f;
    float p10 = (kA < L) ? __expf(a10) : 0.f;
    float p01 = (kB < L) ? __expf(a01) : 0.f;
    float p11 = (kB < L) ? __expf(a11) : 0.f;

    float* s0 = St + ((size_t)b * NQ + q0 + qi) * NK;
    float* s1 = St + ((size_t)b * NQ + q0 + qi + 16) * NK;
    s0[kA] = p00; s0[kB] = p01;
    s1[kA] = p10; s1[kB] = p11;

    // deterministic per-chunk row sums (reduce over ki = low 4 lane bits)
    float r0s = p00 + p01, r1s = p10 + p11;
#pragma unroll
    for (int o = 1; o <= 8; o <<= 1) {
        r0s += __shfl_xor(r0s, o, 64);
        r1s += __shfl_xor(r1s, o, 64);
    }
    if (ki == 0) {
        Psum[((size_t)b * NQ + q0 + qi) * 32 + kc] = r0s;
        Psum[((size_t)b * NQ + q0 + qi + 16) * 32 + kc] = r1s;
    }
}

// ---------------- K3: PV GEMM + normalize ----------------
// 32q x 32d per block, 4x4 micro, 4-way k-split across waves (2B/FMA LDS),
// register-staged double buffering. out = (P @ V) / rowsum.
__global__ __launch_bounds__(256) void pv_kernel(
    const float* __restrict__ St, const float* __restrict__ V,
    const float* __restrict__ Psum, const int* __restrict__ vlen,
    float* __restrict__ out)
{
    __shared__ __align__(16) float sPt[2][32][36];   // [k][q]
    __shared__ __align__(16) float sV[2][32][36];    // [k][d]
    __shared__ float sAll[3][64][17];
    __shared__ float sRowsum[32];

    int bid = blockIdx.x;
    int b = bid & 3;
    int rest = bid >> 2;
    int qt = rest >> 3, dt = rest & 7;
    int q0 = qt * 32, d0 = dt * 32;
    int L = vlen[b];
    int nc = (L + 31) >> 5;

    int tid = threadIdx.x;
    if (tid < 32) {
        float s = 0.f;
        const float* pp = Psum + ((size_t)b * NQ + q0 + tid) * 32;
        for (int c = 0; c < nc; ++c) s += pp[c];
        sRowsum[tid] = s;
    }

    int r = tid >> 3, c4 = tid & 7;                  // stagers
    int w = tid >> 6, sp = tid & 63;                 // k-split wave, spatial
    int qg = sp >> 3, dg = sp & 7;

    const float* Stb = St + ((size_t)b * NQ + q0 + r) * NK;
    const float* Vb  = V + (size_t)b * NK * DD + d0;

    float4 pf = *(const float4*)(Stb + c4 * 4);
    float4 vf = *(const float4*)(Vb + (size_t)r * DD + c4 * 4);

    float acc[4][4] = {};

    for (int c = 0; c < nc; ++c) {
        int cur = c & 1;
        sPt[cur][c4 * 4 + 0][r] = pf.x;
        sPt[cur][c4 * 4 + 1][r] = pf.y;
        sPt[cur][c4 * 4 + 2][r] = pf.z;
        sPt[cur][c4 * 4 + 3][r] = pf.w;
        *(float4*)&sV[cur][r][c4 * 4] = vf;
        if (c + 1 < nc) {
            int kn = (c + 1) * 32;
            pf = *(const float4*)(Stb + kn + c4 * 4);
            vf = *(const float4*)(Vb + (size_t)(kn + r) * DD + c4 * 4);
        }
        __syncthreads();
#pragma unroll
        for (int kk = 0; kk < 8; ++kk) {
            float4 A  = *(const float4*)&sPt[cur][w * 8 + kk][qg * 4];
            float4 Bv = *(const float4*)&sV[cur][w * 8 + kk][dg * 4];
            acc[0][0] = fmaf(A.x, Bv.x, acc[0][0]);
            acc[0][1] = fmaf(A.x, Bv.y, acc[0][1]);
            acc[0][2] = fmaf(A.x, Bv.z, acc[0][2]);
            acc[0][3] = fmaf(A.x, Bv.w, acc[0][3]);
            acc[1][0] = fmaf(A.y, Bv.x, acc[1][0]);
            acc[1][1] = fmaf(A.y, Bv.y, acc[1][1]);
            acc[1][2] = fmaf(A.y, Bv.z, acc[1][2]);
            acc[1][3] = fmaf(A.y, Bv.w, acc[1][3]);
            acc[2][0] = fmaf(A.z, Bv.x, acc[2][0]);
            acc[2][1] = fmaf(A.z, Bv.y, acc[2][1]);
            acc[2][2] = fmaf(A.z, Bv.z, acc[2][2]);
            acc[2][3] = fmaf(A.z, Bv.w, acc[2][3]);
            acc[3][0] = fmaf(A.w, Bv.x, acc[3][0]);
            acc[3][1] = fmaf(A.w, Bv.y, acc[3][1]);
            acc[3][2] = fmaf(A.w, Bv.z, acc[3][2]);
            acc[3][3] = fmaf(A.w, Bv.w, acc[3][3]);
        }
    }

    // cross-wave k-split reduction (deterministic)
    if (w > 0) {
#pragma unroll
        for (int i = 0; i < 4; ++i)
#pragma unroll
            for (int j = 0; j < 4; ++j) sAll[w - 1][sp][i * 4 + j] = acc[i][j];
    }
    __syncthreads();
    if (w == 0) {
#pragma unroll
        for (int ww = 0; ww < 3; ++ww)
#pragma unroll
            for (int i = 0; i < 4; ++i)
#pragma unroll
                for (int j = 0; j < 4; ++j) acc[i][j] += sAll[ww][sp][i * 4 + j];
#pragma unroll
        for (int i = 0; i < 4; ++i) {
            float inv = 1.0f / sRowsum[qg * 4 + i];
            float4 o = { acc[i][0] * inv, acc[i][1] * inv,
                         acc[i][2] * inv, acc[i][3] * inv };
            *(float4*)&out[((size_t)b * NQ + q0 + qg * 4 + i) * DD + d0 + dg * 4] = o;
        }
    }
}

extern "C" void kernel_launch(void* const* d_in, const int* in_sizes, int n_in,
                              void* d_out, int out_size, void* d_ws, size_t ws_size,
                              hipStream_t stream) {
    const float* queries = (const float*)d_in[0];  // [B,NQ,D]
    const float* keys    = (const float*)d_in[1];  // [B,NK,D]
    const float* values  = (const float*)d_in[2];  // [B,NK,D]
    const int*   vlens   = (const int*)d_in[3];    // [B]
    const float* Wq      = (const float*)d_in[4];  // [D,H]
    const float* Wk      = (const float*)d_in[5];  // [D,H]
    const float* wv      = (const float*)d_in[6];  // [H]
    float* out = (float*)d_out;

    float* tq   = (float*)d_ws;                          // 1 MB
    float* tk   = tq + (size_t)BB * NQ * HH;             // 4 MB
    float* St   = tk + (size_t)BB * NK * HH;             // 4 MB  (P, [b][q][k])
    float* Psum = St + (size_t)BB * NQ * NK;             // 128 KB [b][q][32]

    dim3 pgrid((BB * NQ) / TM + (BB * NK) / TM, HH / TN);   // (80,4)
    proj_tanh_kernel<<<pgrid, 256, 0, stream>>>(queries, keys, Wq, Wk, tq, tk);

    scores_kernel<<<dim3(BB * (NQ / 32) * (NK / 32)), 256, 0, stream>>>(
        tq, tk, wv, vlens, St, Psum);

    pv_kernel<<<dim3(BB * (NQ / 32) * (DD / 32)), 256, 0, stream>>>(
        St, values, Psum, vlens, out);
}